// Round 1
// baseline (395.315 us; speedup 1.0000x reference)
//
#include <hip/hip_runtime.h>
#include <stdint.h>

// Problem constants (B=2, S=2048, D=2048, H=16, HD=128)
#define S_LEN 2048
#define DMODEL 2048
#define NHEAD 16
#define HDIM 128

typedef __attribute__((ext_vector_type(8))) short short8;   // 8 bf16 (4 VGPRs)
typedef __attribute__((ext_vector_type(4))) float floatx4;  // MFMA acc

__device__ __forceinline__ unsigned short f2b(float f) {
  union { float f; unsigned u; } v; v.f = f;
  unsigned r = v.u + 0x7FFFu + ((v.u >> 16) & 1u);  // RNE
  return (unsigned short)(r >> 16);
}

// async global->LDS, 16B per lane; LDS dest is wave-uniform base + lane*16
__device__ __forceinline__ void load_lds16(const unsigned short* g, unsigned short* l) {
  __builtin_amdgcn_global_load_lds((const __attribute__((address_space(1))) void*)g,
                                   (__attribute__((address_space(3))) void*)l, 16, 0, 0);
}

// ---------------- fused fp32 -> bf16 conversion (x in 2 slices + 4 weights) ----------------
__global__ __launch_bounds__(256) void cvt_all(const float* __restrict__ x,
                                               const float* __restrict__ Wq, const float* __restrict__ Wk,
                                               const float* __restrict__ Wv, const float* __restrict__ Wo,
                                               unsigned short* __restrict__ xb,
                                               unsigned short* __restrict__ Wqb, unsigned short* __restrict__ Wkb,
                                               unsigned short* __restrict__ Wvb, unsigned short* __restrict__ Wob) {
  const size_t idx = (size_t)blockIdx.x * 256 + threadIdx.x;  // < 2^20 per slice
  const int y = blockIdx.y;
  const float4* s; ushort4* d;
  if (y == 0)      { s = (const float4*)x;               d = (ushort4*)xb; }
  else if (y == 1) { s = (const float4*)x + (1u << 20);  d = (ushort4*)xb + (1u << 20); }
  else if (y == 2) { s = (const float4*)Wq;              d = (ushort4*)Wqb; }
  else if (y == 3) { s = (const float4*)Wk;              d = (ushort4*)Wkb; }
  else if (y == 4) { s = (const float4*)Wv;              d = (ushort4*)Wvb; }
  else             { s = (const float4*)Wo;              d = (ushort4*)Wob; }
  float4 f = s[idx];
  ushort4 o;
  o.x = f2b(f.x); o.y = f2b(f.y); o.z = f2b(f.z); o.w = f2b(f.w);
  d[idx] = o;
}

// ---------------- 256x256 8-phase GEMM (T2+T3+T4+T5) ----------------
// C = A @ Bw^T + bias. A:[M,K] bf16, Bw:[N,K] bf16 (weight row = C col). K = 2048.
// 512 threads = 8 waves (wm 0..1 x wn 0..3); per-wave C tile = 128x64 -> acc[8][4].
// LDS: [buf2][op2(A,B)][ks2(k-half of 32)][256 rows][32 k] bf16 = 128 KB total.
//   Within a (buf,op,ks) region: byte = row*64 + slot*16, stored slot = logical ^ ((row>>1)&3)
//   -> ds_read_b128 fragment reads are 2-way per 16-lane pass (free).
//   A k-half (16 KB) is linear per 1024B wave-chunk -> valid global_load_lds dest.
// Schedule: 8 phases per 2 K-tiles (buf0 = even K-tile, buf1 = odd). One half-tile
// (2 gload_lds per wave) staged per phase; stage always lands >=2 barriers after the
// target region's last read. Counted s_waitcnt vmcnt(4) ONLY at phases 4 and 8.
// MODE 0: bf16 row-major [M,2048]; MODE 1: bf16 V^T [(b*D+col)*S + s]; MODE 2: fp32 row-major.

#define REG256(buf, op, ks) (lds + ((((buf)*2 + (op)) * 2 + (ks)) * 8192))
#define STAGE256(buf, op, ks, kt)                                                    \
  do {                                                                               \
    unsigned short* _d = REG256(buf, op, ks);                                        \
    const unsigned short* _g0 = ((op) ? gB[0] : gA[0]) + (kt) * 64 + (ks) * 32;      \
    const unsigned short* _g1 = ((op) ? gB[1] : gA[1]) + (kt) * 64 + (ks) * 32;      \
    load_lds16(_g0, _d + ldso[0]);                                                   \
    load_lds16(_g1, _d + ldso[1]);                                                   \
  } while (0)
#define RDA256(buf, ks)                                                              \
  { _Pragma("unroll") for (int mf = 0; mf < 8; mf++)                                 \
      av[mf] = *(const short8*)(REG256(buf, 0, ks) + aoff + mf * 512); }
#define RDB256(buf, ks, nh)                                                          \
  { bv[0] = *(const short8*)(REG256(buf, 1, ks) + boff + (nh) * 1024);               \
    bv[1] = *(const short8*)(REG256(buf, 1, ks) + boff + (nh) * 1024 + 512); }
#define MFMACL256(nh)                                                                \
  { __builtin_amdgcn_s_setprio(1);                                                   \
    _Pragma("unroll") for (int mf = 0; mf < 8; mf++) {                               \
      acc[mf][(nh)*2]   = __builtin_amdgcn_mfma_f32_16x16x32_bf16(av[mf], bv[0], acc[mf][(nh)*2],   0, 0, 0); \
      acc[mf][(nh)*2+1] = __builtin_amdgcn_mfma_f32_16x16x32_bf16(av[mf], bv[1], acc[mf][(nh)*2+1], 0, 0, 0); } \
    __builtin_amdgcn_s_setprio(0); }
#define BAR256 __builtin_amdgcn_s_barrier()
#define LGKM0 do { asm volatile("s_waitcnt lgkmcnt(0)" ::: "memory"); __builtin_amdgcn_sched_barrier(0); } while (0)
#define VMC4 asm volatile("s_waitcnt vmcnt(4)" ::: "memory")

__device__ __forceinline__ void gemm256_body(const unsigned short* __restrict__ A,
                                             const unsigned short* __restrict__ Bw,
                                             const float* __restrict__ bias,
                                             void* __restrict__ out, int mode, float scale,
                                             int m0, int n0, unsigned short* lds) {
  const int K = DMODEL;
  const int t = threadIdx.x;
  const int lane = t & 63, w = t >> 6;
  const int quad = lane >> 4, lc = lane & 15;
  const int wm = w >> 2, wn = w & 3;

  // staging geometry: wave chunk c = w*2+i covers rows c*16 + (lane>>2) of the tile,
  // lane's stored slot = lane&3; it must FETCH logical k-chunk (lane&3)^((row>>1)&3)
  // = (lane&3)^((lane>>3)&3) since (c*16)>>1 is a multiple of 4.
  const int chunkoff = ((lane & 3) ^ ((lane >> 3) & 3)) * 8;
  const unsigned short* gA[2];
  const unsigned short* gB[2];
  int ldso[2];
#pragma unroll
  for (int i = 0; i < 2; i++) {
    const int c = w * 2 + i;
    const int r = c * 16 + (lane >> 2);
    gA[i] = A + (size_t)(m0 + r) * K + chunkoff;
    gB[i] = Bw + (size_t)(n0 + r) * K + chunkoff;
    ldso[i] = c * 512 + lane * 8;  // ushort offset inside an 8192-ushort region
  }

  // fragment read offsets: row -> (row)*32 ushorts, slot = quad ^ ((row>>1)&3) = quad ^ ((lc>>1)&3)
  const int rsw = ((lc >> 1) & 3);
  const int aoff = (wm * 128 + lc) * 32 + ((quad ^ rsw) * 8);
  const int boff = (wn * 64 + lc) * 32 + ((quad ^ rsw) * 8);

  floatx4 acc[8][4] = {};
  short8 av[8], bv[2];

  // prologue: K-tile 0 (all 4 halves) + K-tile 1 k-half0 (A,B). 12 loads/wave.
  STAGE256(0, 0, 0, 0); STAGE256(0, 1, 0, 0); STAGE256(0, 0, 1, 0); STAGE256(0, 1, 1, 0);
  STAGE256(1, 0, 0, 1); STAGE256(1, 1, 0, 1);
  VMC4;    // oldest 8 (= all of K-tile 0) landed; T1-ks0 still in flight
  BAR256;

  const int NKT = K / 64;      // 32
  const int NIT = NKT / 2;     // 16
  for (int it = 0; it < NIT; it++) {
    const int kt1 = 2 * it + 1;
    const int kt2 = (2 * it + 2 < NKT) ? 2 * it + 2 : NKT - 1;  // clamped prefetch keeps
    const int kt3 = (2 * it + 3 < NKT) ? 2 * it + 3 : NKT - 1;  // vmcnt counts uniform
    // ph1: buf0 ks0 nh0                       stage buf1.A.ks1 <- T1
    RDA256(0, 0); RDB256(0, 0, 0); STAGE256(1, 0, 1, kt1); BAR256; LGKM0; MFMACL256(0); BAR256;
    // ph2: buf0 ks0 nh1                       stage buf1.B.ks1 <- T1
    RDB256(0, 0, 1);               STAGE256(1, 1, 1, kt1); BAR256; LGKM0; MFMACL256(1); BAR256;
    // ph3: buf0 ks1 nh0                       stage buf0.A.ks0 <- T2 (A.ks0 last read ph1)
    RDA256(0, 1); RDB256(0, 1, 0); STAGE256(0, 0, 0, kt2); BAR256; LGKM0; MFMACL256(0); BAR256;
    // ph4: buf0 ks1 nh1                       stage buf0.B.ks0 <- T2 ; vmcnt(4)
    RDB256(0, 1, 1);               STAGE256(0, 1, 0, kt2); BAR256; LGKM0; MFMACL256(1); VMC4; BAR256;
    // ph5: buf1 ks0 nh0 (T1 ks0 landed ^)     stage buf0.A.ks1 <- T2 (last read ph3)
    RDA256(1, 0); RDB256(1, 0, 0); STAGE256(0, 0, 1, kt2); BAR256; LGKM0; MFMACL256(0); BAR256;
    // ph6: buf1 ks0 nh1                       stage buf0.B.ks1 <- T2
    RDB256(1, 0, 1);               STAGE256(0, 1, 1, kt2); BAR256; LGKM0; MFMACL256(1); BAR256;
    // ph7: buf1 ks1 nh0 (T1 ks1 landed @ph4)  stage buf1.A.ks0 <- T3 (last read ph5)
    RDA256(1, 1); RDB256(1, 1, 0); STAGE256(1, 0, 0, kt3); BAR256; LGKM0; MFMACL256(0); BAR256;
    // ph8: buf1 ks1 nh1                       stage buf1.B.ks0 <- T3 ; vmcnt(4) -> T2 fully landed
    RDB256(1, 1, 1);               STAGE256(1, 1, 0, kt3); BAR256; LGKM0; MFMACL256(1); VMC4; BAR256;
  }

  // epilogue: C/D frag row = quad*4 + r (A side), col = lc (B side)
#pragma unroll
  for (int nf = 0; nf < 4; nf++) {
    const int col = n0 + wn * 64 + nf * 16 + lc;
    const float bcol = bias[col];
#pragma unroll
    for (int mf = 0; mf < 8; mf++) {
      const int row0 = m0 + wm * 128 + mf * 16 + quad * 4;
      if (mode == 1) {
        ushort4 o;
        o.x = f2b((acc[mf][nf][0] + bcol) * scale);
        o.y = f2b((acc[mf][nf][1] + bcol) * scale);
        o.z = f2b((acc[mf][nf][2] + bcol) * scale);
        o.w = f2b((acc[mf][nf][3] + bcol) * scale);
        const int b = row0 >> 11;          // row0 / S_LEN
        const int s = row0 & (S_LEN - 1);
        *(ushort4*)&((unsigned short*)out)[((size_t)(b * DMODEL + col)) * S_LEN + s] = o;
      } else if (mode == 2) {
#pragma unroll
        for (int r = 0; r < 4; r++)
          ((float*)out)[(size_t)(row0 + r) * DMODEL + col] = (acc[mf][nf][r] + bcol) * scale;
      } else {
#pragma unroll
        for (int r = 0; r < 4; r++)
          ((unsigned short*)out)[(size_t)(row0 + r) * DMODEL + col] = f2b((acc[mf][nf][r] + bcol) * scale);
      }
    }
  }
}

// fused QKV: grid (24, 16); col-tiles 0-7 -> Q, 8-15 -> K, 16-23 -> V (V^T epilogue)
__global__ __launch_bounds__(512, 2)
void qkv256(const unsigned short* __restrict__ xb,
            const unsigned short* __restrict__ Wqb, const unsigned short* __restrict__ Wkb,
            const unsigned short* __restrict__ Wvb,
            const float* __restrict__ bq, const float* __restrict__ bk, const float* __restrict__ bvp,
            unsigned short* __restrict__ Qb, unsigned short* __restrict__ Kb,
            unsigned short* __restrict__ Vtb, float qscale) {
  __shared__ unsigned short lds[65536];  // 128 KB
  const int sel = blockIdx.x >> 3;
  const int n0 = (blockIdx.x & 7) * 256;
  const int m0 = blockIdx.y * 256;
  const unsigned short* Bw = (sel == 0) ? Wqb : (sel == 1) ? Wkb : Wvb;
  const float* bias = (sel == 0) ? bq : (sel == 1) ? bk : bvp;
  void* out = (sel == 0) ? (void*)Qb : (sel == 1) ? (void*)Kb : (void*)Vtb;
  const float scale = (sel == 0) ? qscale : 1.f;
  const int mode = (sel == 2) ? 1 : 0;
  gemm256_body(xb, Bw, bias, out, mode, scale, m0, n0, lds);
}

// output projection: grid (8, 16), fp32 out
__global__ __launch_bounds__(512, 2)
void out256(const unsigned short* __restrict__ Ob, const unsigned short* __restrict__ Wob,
            const float* __restrict__ bo, float* __restrict__ out) {
  __shared__ unsigned short lds[65536];
  gemm256_body(Ob, Wob, bo, out, 2, 1.f, blockIdx.y * 256, blockIdx.x * 256, lds);
}

// ---------------- Flash attention (causal), BM=128, S^T orientation ----------------
// Q,K: [b,s,h,hd] rows of [B*S, D]; Vt: [b,h,hd,s]; O: [b,s,h,hd].
// Q pre-scaled by log2(e)/sqrt(HD) so softmax uses exp2.
__global__ __launch_bounds__(256, 2)
void attn_fwd(const unsigned short* __restrict__ Qg, const unsigned short* __restrict__ Kg,
              const unsigned short* __restrict__ Vtg, unsigned short* __restrict__ Og) {
  __shared__ unsigned short Ks[2][64 * 128];  // 32 KB [buf][krow][chunk^(krow&15)]
  __shared__ unsigned short Vs[128 * 64];     // 16 KB [hd][chunk^(hd&7)]
  __shared__ unsigned short Ps[128 * 72];     // 18 KB [query][key], pitch 72 spreads banks

  const int t = threadIdx.x;
  const int lane = t & 63, w = t >> 6;
  const int quad = lane >> 4, lc = lane & 15;
  const int y = blockIdx.y;
  const int tile = (y < 16) ? (int)blockIdx.x : 15 - (int)blockIdx.x;
  const int b = y >> 4, h = y & 15;
  const size_t qkbase = (size_t)b * S_LEN * DMODEL + h * HDIM;
  const size_t vtbase = ((size_t)(b * DMODEL + h * HDIM)) * S_LEN;
  const int q0 = tile * 128;
  const int wrow = q0 + w * 32;  // wave's first q-row

  short8 aq[2][4];
#pragma unroll
  for (int pm = 0; pm < 2; pm++)
#pragma unroll
    for (int ks = 0; ks < 4; ks++)
      aq[pm][ks] = *(const short8*)&Qg[qkbase + (size_t)(wrow + pm * 16 + lc) * DMODEL + ks * 32 + quad * 8];

  const unsigned short* kga[4];
  const unsigned short* vga[4];
  int kloff[4], vloff[4];
#pragma unroll
  for (int i = 0; i < 4; i++) {
    int c = w * 4 + i;
    int krow = 4 * c + (lane >> 4);
    kga[i] = Kg + qkbase + (size_t)krow * DMODEL + ((lane & 15) ^ (krow & 15)) * 8;
    kloff[i] = c * 512 + lane * 8;
    int vrow = 8 * c + (lane >> 3);
    vga[i] = Vtg + vtbase + (size_t)vrow * S_LEN + ((lane & 7) ^ (vrow & 7)) * 8;
    vloff[i] = c * 512 + lane * 8;
  }

  floatx4 oaccT[8][2] = {};
  float m_run[2] = {-1e30f, -1e30f}, l_run[2] = {0.f, 0.f};

  const int kiters = 2 * tile + 2;

#pragma unroll
  for (int i = 0; i < 4; i++) load_lds16(kga[i], &Ks[0][kloff[i]]);

  for (int kb = 0; kb < kiters; kb++) {
    const int k0 = kb * 64;
    const int cur = kb & 1;
    __syncthreads();

#pragma unroll
    for (int i = 0; i < 4; i++) load_lds16(vga[i] + k0, &Vs[vloff[i]]);
    {
      const size_t knext = (size_t)((kb + 1 < kiters) ? k0 + 64 : k0) * DMODEL;
#pragma unroll
      for (int i = 0; i < 4; i++) load_lds16(kga[i] + knext, &Ks[cur ^ 1][kloff[i]]);
    }

    const bool hasw = (k0 <= wrow + 31);
    float alpha[2];
    if (hasw) {
      floatx4 st[4][2];
#pragma unroll
      for (int mt = 0; mt < 4; mt++)
#pragma unroll
        for (int pm = 0; pm < 2; pm++) st[mt][pm] = (floatx4){0.f, 0.f, 0.f, 0.f};
#pragma unroll
      for (int ks = 0; ks < 4; ks++) {
        short8 kf[4];
#pragma unroll
        for (int mt = 0; mt < 4; mt++) {
          int n = mt * 16 + lc;
          kf[mt] = *(const short8*)&Ks[cur][n * 128 + (((ks * 4 + quad) ^ (n & 15)) * 8)];
        }
#pragma unroll
        for (int mt = 0; mt < 4; mt++)
#pragma unroll
          for (int pm = 0; pm < 2; pm++)
            st[mt][pm] = __builtin_amdgcn_mfma_f32_16x16x32_bf16(kf[mt], aq[pm][ks], st[mt][pm], 0, 0, 0);
      }

      float mx[2] = {-1e30f, -1e30f};
      if (k0 + 63 > wrow) {
#pragma unroll
        for (int pm = 0; pm < 2; pm++) {
          const int qq = wrow + pm * 16 + lc;
#pragma unroll
          for (int mt = 0; mt < 4; mt++) {
            const int key = k0 + mt * 16 + quad * 4;
#pragma unroll
            for (int r = 0; r < 4; r++) {
              if (key + r > qq) st[mt][pm][r] = -1e30f;
              mx[pm] = fmaxf(mx[pm], st[mt][pm][r]);
            }
          }
        }
      } else {
#pragma unroll
        for (int pm = 0; pm < 2; pm++)
#pragma unroll
          for (int mt = 0; mt < 4; mt++)
#pragma unroll
            for (int r = 0; r < 4; r++) mx[pm] = fmaxf(mx[pm], st[mt][pm][r]);
      }
#pragma unroll
      for (int pm = 0; pm < 2; pm++) {
        mx[pm] = fmaxf(mx[pm], __shfl_xor(mx[pm], 16));
        mx[pm] = fmaxf(mx[pm], __shfl_xor(mx[pm], 32));
        float mnew = fmaxf(m_run[pm], mx[pm]);
        alpha[pm] = __builtin_amdgcn_exp2f(m_run[pm] - mnew);
        m_run[pm] = mnew;
        l_run[pm] *= alpha[pm];
      }

#pragma unroll
      for (int pm = 0; pm < 2; pm++)
#pragma unroll
        for (int mt = 0; mt < 4; mt++) {
          float p0 = __builtin_amdgcn_exp2f(st[mt][pm][0] - m_run[pm]);
          float p1 = __builtin_amdgcn_exp2f(st[mt][pm][1] - m_run[pm]);
          float p2 = __builtin_amdgcn_exp2f(st[mt][pm][2] - m_run[pm]);
          float p3 = __builtin_amdgcn_exp2f(st[mt][pm][3] - m_run[pm]);
          l_run[pm] += (p0 + p1) + (p2 + p3);
          ushort4 o;
          o.x = f2b(p0); o.y = f2b(p1); o.z = f2b(p2); o.w = f2b(p3);
          *(ushort4*)&Ps[(w * 32 + pm * 16 + lc) * 72 + mt * 16 + quad * 4] = o;
        }
    }

    asm volatile("s_waitcnt vmcnt(4)\n\ts_barrier" ::: "memory");

    if (hasw) {
#pragma unroll
      for (int mt8 = 0; mt8 < 8; mt8++)
#pragma unroll
        for (int pm = 0; pm < 2; pm++) {
          oaccT[mt8][pm][0] *= alpha[pm]; oaccT[mt8][pm][1] *= alpha[pm];
          oaccT[mt8][pm][2] *= alpha[pm]; oaccT[mt8][pm][3] *= alpha[pm];
        }

#pragma unroll
      for (int ks = 0; ks < 2; ks++) {
        short8 pf[2];
#pragma unroll
        for (int pm = 0; pm < 2; pm++)
          pf[pm] = *(const short8*)&Ps[(w * 32 + pm * 16 + lc) * 72 + ks * 32 + quad * 8];
#pragma unroll
        for (int mt8 = 0; mt8 < 8; mt8++) {
          int n = mt8 * 16 + lc;
          short8 vf = *(const short8*)&Vs[n * 64 + (((ks * 4 + quad) ^ (n & 7)) * 8)];
#pragma unroll
          for (int pm = 0; pm < 2; pm++)
            oaccT[mt8][pm] = __builtin_amdgcn_mfma_f32_16x16x32_bf16(vf, pf[pm], oaccT[mt8][pm], 0, 0, 0);
        }
      }
    }
  }

#pragma unroll
  for (int pm = 0; pm < 2; pm++) {
    l_run[pm] += __shfl_xor(l_run[pm], 16);
    l_run[pm] += __shfl_xor(l_run[pm], 32);
    float inv = 1.f / l_run[pm];
    size_t obase = ((size_t)(b * S_LEN + wrow + pm * 16 + lc)) * DMODEL + h * HDIM;
#pragma unroll
    for (int mt8 = 0; mt8 < 8; mt8++) {
      ushort4 o;
      o.x = f2b(oaccT[mt8][pm][0] * inv);
      o.y = f2b(oaccT[mt8][pm][1] * inv);
      o.z = f2b(oaccT[mt8][pm][2] * inv);
      o.w = f2b(oaccT[mt8][pm][3] * inv);
      *(ushort4*)&Og[obase + mt8 * 16 + quad * 4] = o;
    }
  }
}

// ---------------- launch ----------------
extern "C" void kernel_launch(void* const* d_in, const int* in_sizes, int n_in,
                              void* d_out, int out_size, void* d_ws, size_t ws_size,
                              hipStream_t stream) {
  const float* x  = (const float*)d_in[0];
  const float* Wq = (const float*)d_in[1];
  const float* bq = (const float*)d_in[2];
  const float* Wk = (const float*)d_in[3];
  const float* bk = (const float*)d_in[4];
  const float* Wv = (const float*)d_in[5];
  const float* bv = (const float*)d_in[6];
  const float* Wo = (const float*)d_in[7];
  const float* bo = (const float*)d_in[8];

  char* w = (char*)d_ws;  // needs 112 MB
  unsigned short* xb  = (unsigned short*)(w);
  unsigned short* Wqb = (unsigned short*)(w + (size_t)16 * (1 << 20));
  unsigned short* Wkb = (unsigned short*)(w + (size_t)24 * (1 << 20));
  unsigned short* Wvb = (unsigned short*)(w + (size_t)32 * (1 << 20));
  unsigned short* Wob = (unsigned short*)(w + (size_t)40 * (1 << 20));
  unsigned short* Qb  = (unsigned short*)(w + (size_t)48 * (1 << 20));
  unsigned short* Kb  = (unsigned short*)(w + (size_t)64 * (1 << 20));
  unsigned short* Vtb = (unsigned short*)(w + (size_t)80 * (1 << 20));
  unsigned short* Ob  = (unsigned short*)(w + (size_t)96 * (1 << 20));

  cvt_all<<<dim3(4096, 6), 256, 0, stream>>>(x, Wq, Wk, Wv, Wo, xb, Wqb, Wkb, Wvb, Wob);

  // Q scale: log2(e)/sqrt(128) so attention softmax can use exp2 directly
  const float qscale = 0.08838834764831843f * 1.4426950408889634f;
  qkv256<<<dim3(24, 16), 512, 0, stream>>>(xb, Wqb, Wkb, Wvb, bq, bk, bv, Qb, Kb, Vtb, qscale);

  attn_fwd<<<dim3(16, 32), 256, 0, stream>>>(Qb, Kb, Vtb, Ob);

  out256<<<dim3(8, 16), 512, 0, stream>>>(Ob, Wob, bo, (float*)d_out);
}